// Round 1
// baseline (4322.733 us; speedup 1.0000x reference)
//
#include <hip/hip_runtime.h>
#include <math.h>

#define B_ 16
#define T_ 4096
#define D_ 1024
#define HID_ 1365
#define N_TOK (B_*T_)
#define RHO_ 0.2f
#define LN_EPS_ 1e-5f

// GEMM tiling
#define MT 128
#define HT 128
#define BK 32
#define LDA 132   // padded leading dim (k-major LDS tiles), 132%4==0 keeps b128 alignment

// ---------------- Kernel 1: LayerNorm statistics (one wave per token) ----------------
__global__ __launch_bounds__(256) void ln_stats_kernel(
    const float* __restrict__ emb, const float* __restrict__ attn,
    float* __restrict__ mu, float* __restrict__ rstd)
{
  int tid = threadIdx.x;
  int wave = tid >> 6, lane = tid & 63;
  int token = blockIdx.x * 4 + wave;
  const float* p = emb + (size_t)token * D_;
  float a = attn[token];
  float s = 0.f, sq = 0.f;
#pragma unroll
  for (int q = 0; q < 4; ++q) {
    float4 v = *reinterpret_cast<const float4*>(p + lane * 4 + q * 256);
    v.x *= a; v.y *= a; v.z *= a; v.w *= a;
    s  += v.x + v.y + v.z + v.w;
    sq += v.x * v.x + v.y * v.y + v.z * v.z + v.w * v.w;
  }
#pragma unroll
  for (int off = 32; off > 0; off >>= 1) {
    s  += __shfl_down(s, off, 64);
    sq += __shfl_down(sq, off, 64);
  }
  if (lane == 0) {
    float m = s * (1.f / D_);
    float var = sq * (1.f / D_) - m * m;
    if (var < 0.f) var = 0.f;
    mu[token] = m;
    rstd[token] = 1.f / sqrtf(var + LN_EPS_);
  }
}

// ---------------- Kernel 2: fused LN-apply + fc1 GEMM + GELU + fc2 dot -> scores ----
// Block: 256 threads (tx=tid&15, ty=tid>>4), tile 128 tokens x 128 hidden, BK=32.
// Each thread: 8x8 micro-tile, rows {tx*4+i, 64+tx*4+i}, cols {ty*4+j, 64+ty*4+j}.
__global__ __launch_bounds__(256) void mlp_score_kernel(
    const float* __restrict__ emb, const float* __restrict__ attn,
    const float* __restrict__ lnw, const float* __restrict__ lnb,
    const float* __restrict__ mu, const float* __restrict__ rstd,
    const float* __restrict__ fc1w, const float* __restrict__ fc1b,
    const float* __restrict__ fc2w, const float* __restrict__ fc2b,
    float* __restrict__ scores)
{
  __shared__ float As[BK * LDA];
  __shared__ float Bs[BK * LDA];
  int tid = threadIdx.x;
  int tx = tid & 15, ty = tid >> 4;
  int m0 = blockIdx.x * MT;

  float pscore[8];
#pragma unroll
  for (int i = 0; i < 8; ++i) pscore[i] = 0.f;

  const int NHT = (HID_ + HT - 1) / HT;  // 11
  for (int ht = 0; ht < NHT; ++ht) {
    int h0 = ht * HT;
    float acc[8][8];
#pragma unroll
    for (int i = 0; i < 8; ++i)
#pragma unroll
      for (int j = 0; j < 8; ++j) acc[i][j] = 0.f;

    for (int k0 = 0; k0 < D_; k0 += BK) {
      __syncthreads();
      // ---- stage A (128 tokens x 32 k), LN fused, k-major transposed store ----
#pragma unroll
      for (int it = 0; it < 4; ++it) {
        int idx = tid + it * 256;       // 0..1023
        int row = idx >> 3, c4 = idx & 7;
        int token = m0 + row;
        float4 e = *reinterpret_cast<const float4*>(emb + (size_t)token * D_ + k0 + c4 * 4);
        float av = attn[token], muv = mu[token], rs = rstd[token];
        float4 w  = *reinterpret_cast<const float4*>(lnw + k0 + c4 * 4);
        float4 bb = *reinterpret_cast<const float4*>(lnb + k0 + c4 * 4);
        int kb = c4 * 4;
        As[(kb + 0) * LDA + row] = (e.x * av - muv) * rs * w.x + bb.x;
        As[(kb + 1) * LDA + row] = (e.y * av - muv) * rs * w.y + bb.y;
        As[(kb + 2) * LDA + row] = (e.z * av - muv) * rs * w.z + bb.z;
        As[(kb + 3) * LDA + row] = (e.w * av - muv) * rs * w.w + bb.w;
      }
      // ---- stage B (128 hidden x 32 k), zero-pad h >= HID ----
#pragma unroll
      for (int it = 0; it < 4; ++it) {
        int idx = tid + it * 256;
        int row = idx >> 3, c4 = idx & 7;
        int h = h0 + row;
        float4 v = make_float4(0.f, 0.f, 0.f, 0.f);
        if (h < HID_) v = *reinterpret_cast<const float4*>(fc1w + (size_t)h * D_ + k0 + c4 * 4);
        int kb = c4 * 4;
        Bs[(kb + 0) * LDA + row] = v.x;
        Bs[(kb + 1) * LDA + row] = v.y;
        Bs[(kb + 2) * LDA + row] = v.z;
        Bs[(kb + 3) * LDA + row] = v.w;
      }
      __syncthreads();
      // ---- compute ----
#pragma unroll 4
      for (int kk = 0; kk < BK; ++kk) {
        float4 a0 = *reinterpret_cast<const float4*>(&As[kk * LDA + tx * 4]);
        float4 a1 = *reinterpret_cast<const float4*>(&As[kk * LDA + 64 + tx * 4]);
        float4 b0 = *reinterpret_cast<const float4*>(&Bs[kk * LDA + ty * 4]);
        float4 b1 = *reinterpret_cast<const float4*>(&Bs[kk * LDA + 64 + ty * 4]);
        float av[8] = {a0.x, a0.y, a0.z, a0.w, a1.x, a1.y, a1.z, a1.w};
        float bv[8] = {b0.x, b0.y, b0.z, b0.w, b1.x, b1.y, b1.z, b1.w};
#pragma unroll
        for (int i = 0; i < 8; ++i)
#pragma unroll
          for (int j = 0; j < 8; ++j)
            acc[i][j] = fmaf(av[i], bv[j], acc[i][j]);
      }
    }
    // ---- epilogue for this h-tile: bias + exact GELU + fc2 weight, accumulate ----
#pragma unroll
    for (int j = 0; j < 8; ++j) {
      int c = h0 + ((j < 4) ? (ty * 4 + j) : (64 + ty * 4 + (j - 4)));
      float b1v = 0.f, w2v = 0.f;
      if (c < HID_) { b1v = fc1b[c]; w2v = fc2w[c]; }
#pragma unroll
      for (int i = 0; i < 8; ++i) {
        float v = acc[i][j] + b1v;
        float gel = 0.5f * v * (1.f + erff(v * 0.70710678118654752440f));
        pscore[i] = fmaf(gel, w2v, pscore[i]);
      }
    }
  }

  // ---- deterministic cross-thread reduction over ty (16 partials per token) ----
  __syncthreads();
  float* red = As;  // 16*128 = 2048 floats <= 4224
#pragma unroll
  for (int i = 0; i < 4; ++i) {
    red[ty * 128 + tx * 4 + i]      = pscore[i];
    red[ty * 128 + 64 + tx * 4 + i] = pscore[4 + i];
  }
  __syncthreads();
  if (tid < 128) {
    float s = fc2b[0];
#pragma unroll
    for (int q = 0; q < 16; ++q) s += red[q * 128 + tid];
    scores[m0 + tid] = s;
  }
}

// ---------------- Kernel 3: per-row masked softmax + entropy + K + z ----------------
__global__ __launch_bounds__(1024) void softmax_kernel(
    const float* __restrict__ scores, const float* __restrict__ attn,
    float* __restrict__ out_z, float* __restrict__ rowent, float* __restrict__ rowK)
{
  __shared__ float buf[1024];
  int b = blockIdx.x, tid = threadIdx.x;
  const float* srow = scores + b * T_;
  const float* arow = attn + b * T_;
  float sv[4], av[4];
#pragma unroll
  for (int q = 0; q < 4; ++q) {
    int t = tid + q * 1024;
    av[q] = arow[t];
    float s = srow[t];
    sv[q] = (av[q] == 0.f) ? -1e9f : s;
  }
  // max
  float m = fmaxf(fmaxf(sv[0], sv[1]), fmaxf(sv[2], sv[3]));
  buf[tid] = m; __syncthreads();
  for (int s = 512; s > 0; s >>= 1) { if (tid < s) buf[tid] = fmaxf(buf[tid], buf[tid + s]); __syncthreads(); }
  m = buf[0]; __syncthreads();
  // exp-sum
  float e[4]; float es = 0.f, as = 0.f;
#pragma unroll
  for (int q = 0; q < 4; ++q) { e[q] = expf(sv[q] - m); es += e[q]; as += av[q]; }
  buf[tid] = es; __syncthreads();
  for (int s = 512; s > 0; s >>= 1) { if (tid < s) buf[tid] += buf[tid + s]; __syncthreads(); }
  es = buf[0]; __syncthreads();
  // attn-sum (exact integers in f32)
  buf[tid] = as; __syncthreads();
  for (int s = 512; s > 0; s >>= 1) { if (tid < s) buf[tid] += buf[tid + s]; __syncthreads(); }
  as = buf[0]; __syncthreads();

  float K = fmaxf(1.f, rintf(RHO_ * as));  // round-half-even matches jnp.round
  float inv = 1.f / es;
  float ent = 0.f;
#pragma unroll
  for (int q = 0; q < 4; ++q) {
    float p = e[q] * inv;
    out_z[b * T_ + tid + q * 1024] = K * p;
    ent -= p * logf(p + 1e-12f);
  }
  buf[tid] = ent; __syncthreads();
  for (int s = 512; s > 0; s >>= 1) { if (tid < s) buf[tid] += buf[tid + s]; __syncthreads(); }
  if (tid == 0) {
    rowent[b] = buf[0] / logf(fmaxf(as, 1.f));
    rowK[b] = K;
  }
}

// ---------------- Kernel 4: per-row exact top-K mask (stable ties) + scalar out ----
__global__ __launch_bounds__(1024) void topk_kernel(
    const float* __restrict__ zall, float* __restrict__ g,
    const float* __restrict__ rowent, const float* __restrict__ rowK,
    float* __restrict__ out_scalar)
{
  __shared__ float sm[T_];
  __shared__ int s_first, s_last;
  int b = blockIdx.x, tid = threadIdx.x;
  const float* zrow = zall + b * T_;
  for (int t = tid; t < T_; t += 1024) sm[t] = zrow[t];
  __syncthreads();
  // bitonic sort, descending
  for (int k = 2; k <= T_; k <<= 1) {
    for (int j = k >> 1; j > 0; j >>= 1) {
      for (int t = tid; t < T_; t += 1024) {
        int ixj = t ^ j;
        if (ixj > t) {
          float a = sm[t], c = sm[ixj];
          bool desc = ((t & k) == 0);
          if (desc ? (a < c) : (a > c)) { sm[t] = c; sm[ixj] = a; }
        }
      }
      __syncthreads();
    }
  }
  int K = (int)rowK[b];
  float thr = sm[K - 1];
  if (tid == 0) { s_first = T_; s_last = -1; }
  __syncthreads();
  for (int t = tid; t < T_; t += 1024) {
    if (sm[t] == thr) { atomicMin(&s_first, t); atomicMax(&s_last, t); }
  }
  __syncthreads();
  int cgt = s_first;                 // count strictly greater than thr
  int eqTotal = s_last - s_first + 1;
  int need = K - cgt;                // >=1 equal elements to take, in index order
  float* grow = g + b * T_;
  bool allEq = (eqTotal == need);
  for (int t = tid; t < T_; t += 1024) {
    float zv = zrow[t];
    if (zv > thr) grow[t] = 1.f;
    else if (zv < thr) grow[t] = 0.f;
    else if (allEq) grow[t] = 1.f;   // all equals selected
  }
  __syncthreads();
  if (!allEq && tid == 0) {
    // rare: more equals than needed -> stable (lowest-index-first) selection
    int cnt = 0;
    for (int t = 0; t < T_; ++t) {
      float zv = zrow[t];
      if (zv == thr) { grow[t] = (cnt < need) ? 1.f : 0.f; ++cnt; }
    }
  }
  if (b == 0 && tid == 0) {
    float s = 0.f;
    for (int i = 0; i < B_; ++i) s += rowent[i];
    out_scalar[0] = s * (1.f / B_);
  }
}

extern "C" void kernel_launch(void* const* d_in, const int* in_sizes, int n_in,
                              void* d_out, int out_size, void* d_ws, size_t ws_size,
                              hipStream_t stream)
{
  const float* emb  = (const float*)d_in[0];
  const float* attn = (const float*)d_in[1];
  const float* lnw  = (const float*)d_in[2];
  const float* lnb  = (const float*)d_in[3];
  const float* fc1w = (const float*)d_in[4];
  const float* fc1b = (const float*)d_in[5];
  const float* fc2w = (const float*)d_in[6];
  const float* fc2b = (const float*)d_in[7];

  float* out = (float*)d_out;
  float* g  = out;                 // [B,T]
  float* z  = out + N_TOK;         // [B,T]
  float* ns = out + 2 * N_TOK;     // [1]

  float* mu     = (float*)d_ws;            // N_TOK
  float* rstd   = mu + N_TOK;              // N_TOK
  float* scores = rstd + N_TOK;            // N_TOK
  float* rowent = scores + N_TOK;          // B_
  float* rowK   = rowent + B_;             // B_

  ln_stats_kernel<<<N_TOK / 4, 256, 0, stream>>>(emb, attn, mu, rstd);
  mlp_score_kernel<<<N_TOK / MT, 256, 0, stream>>>(emb, attn, lnw, lnb, mu, rstd,
                                                   fc1w, fc1b, fc2w, fc2b, scores);
  softmax_kernel<<<B_, 1024, 0, stream>>>(scores, attn, z, rowent, rowK);
  topk_kernel<<<B_, 1024, 0, stream>>>(z, g, rowent, rowK, ns);
}

// Round 2
// 1993.638 us; speedup vs baseline: 2.1683x; 2.1683x over previous
//
#include <hip/hip_runtime.h>
#include <math.h>

#define B_ 16
#define T_ 4096
#define D_ 1024
#define HID_ 1365
#define NPAD 1408            // 88*16, zero-padded hidden
#define NGRP 88              // NPAD/16
#define N_TOK (B_*T_)
#define RHO_ 0.2f
#define LN_EPS_ 1e-5f
#define SC 1024.0f
#define INV_SC2 (1.0f/(1024.0f*1024.0f))

#define MT 128               // tokens per block
#define HT 128               // hidden per block pass
#define NHT 11               // 1408/128
#define KSTEPS 32            // 1024/32
#define LDA 40               // f16 leading dim for A tiles (pad: 80B rows -> 2-way banks, free)
#define WCHUNKS (NGRP*32*4*16)   // 180224 fragment chunks of 16B

typedef _Float16 f16x8 __attribute__((ext_vector_type(8)));
typedef _Float16 f16x4 __attribute__((ext_vector_type(4)));
typedef float f32x4 __attribute__((ext_vector_type(4)));

// ---------------- Kernel 1: LayerNorm statistics (one wave per token) ----------------
__global__ __launch_bounds__(256) void ln_stats_kernel(
    const float* __restrict__ emb, const float* __restrict__ attn,
    float* __restrict__ mu, float* __restrict__ rstd)
{
  int tid = threadIdx.x;
  int wave = tid >> 6, lane = tid & 63;
  int token = blockIdx.x * 4 + wave;
  const float* p = emb + (size_t)token * D_;
  float a = attn[token];
  float s = 0.f, sq = 0.f;
#pragma unroll
  for (int q = 0; q < 4; ++q) {
    float4 v = *reinterpret_cast<const float4*>(p + lane * 4 + q * 256);
    v.x *= a; v.y *= a; v.z *= a; v.w *= a;
    s  += v.x + v.y + v.z + v.w;
    sq += v.x * v.x + v.y * v.y + v.z * v.z + v.w * v.w;
  }
#pragma unroll
  for (int off = 32; off > 0; off >>= 1) {
    s  += __shfl_down(s, off, 64);
    sq += __shfl_down(sq, off, 64);
  }
  if (lane == 0) {
    float m = s * (1.f / D_);
    float var = sq * (1.f / D_) - m * m;
    if (var < 0.f) var = 0.f;
    mu[token] = m;
    rstd[token] = 1.f / sqrtf(var + LN_EPS_);
  }
}

// ---------------- Kernel 1b: split fc1_w (x1024) into hi/lo f16 in MFMA-frag order ---
// chunk c -> ln=c&15, q=(c>>4)&3, ks=(c>>6)&31, g=c>>11 ; n=g*16+ln, k=ks*32+q*8
__global__ __launch_bounds__(256) void wsplit_kernel(
    const float* __restrict__ fc1w, f16x8* __restrict__ whi, f16x8* __restrict__ wlo)
{
  int c = blockIdx.x * 256 + threadIdx.x;
  if (c >= WCHUNKS) return;
  int ln = c & 15, q = (c >> 4) & 3, ks = (c >> 6) & 31, g = c >> 11;
  int n = g * 16 + ln;
  int k = ks * 32 + q * 8;
  f16x8 hi, lo;
#pragma unroll
  for (int j = 0; j < 8; ++j) {
    float v = (n < HID_) ? fc1w[(size_t)n * D_ + k + j] * SC : 0.f;
    _Float16 h = (_Float16)v;
    hi[j] = h;
    lo[j] = (_Float16)(v - (float)h);
  }
  whi[c] = hi;
  wlo[c] = lo;
}

// ---------------- Kernel 2: split-f16 MFMA GEMM + GELU + fc2 dot -> partial scores ---
// grid (512 token-tiles, 11 h-tiles), 256 thr = 4 waves, wave tile 64x64 (4x4 MFMAs)
__global__ __launch_bounds__(256) void mfma_score_kernel(
    const float* __restrict__ emb, const float* __restrict__ attn,
    const float* __restrict__ lnw, const float* __restrict__ lnb,
    const float* __restrict__ mu, const float* __restrict__ rstd,
    const f16x8* __restrict__ whi, const f16x8* __restrict__ wlo,
    const float* __restrict__ fc1b, const float* __restrict__ fc2w,
    float* __restrict__ partial)
{
  __shared__ _Float16 As_hi[MT * LDA];
  __shared__ _Float16 As_lo[MT * LDA];
  __shared__ float red[2][MT];

  int tid = threadIdx.x;
  int lane = tid & 63, w = tid >> 6;
  int m0 = blockIdx.x * MT;
  int ht = blockIdx.y;
  int ln16 = lane & 15, quad = lane >> 4;
  int rowhalf = w & 1, colhalf = w >> 1;

  f32x4 acc[4][4];
#pragma unroll
  for (int i = 0; i < 4; ++i)
#pragma unroll
    for (int j = 0; j < 4; ++j) acc[i][j] = (f32x4)0.f;

  for (int ks = 0; ks < KSTEPS; ++ks) {
    int k0 = ks * 32;
    __syncthreads();
    // ---- stage A: 128 tokens x 32 k, LN fused, split to hi/lo f16 (x1024) ----
#pragma unroll
    for (int it = 0; it < 4; ++it) {
      int idx = tid + it * 256;            // 0..1023
      int row = idx >> 3, c4 = idx & 7;
      int token = m0 + row;
      float4 e  = *reinterpret_cast<const float4*>(emb + (size_t)token * D_ + k0 + c4 * 4);
      float av = attn[token], rs = rstd[token];
      float alpha = av * rs;               // y = (x*a - mu)*rs*w + b = (x*alpha)*w + (b - mu*rs*w)
      float nmr = -mu[token] * rs;
      float4 w4 = *reinterpret_cast<const float4*>(lnw + k0 + c4 * 4);
      float4 b4 = *reinterpret_cast<const float4*>(lnb + k0 + c4 * 4);
      f16x4 hi4, lo4;
      {
        float y = fmaf(e.x * alpha, w4.x, fmaf(nmr, w4.x, b4.x)) * SC;
        _Float16 h = (_Float16)y; hi4[0] = h; lo4[0] = (_Float16)(y - (float)h);
      }
      {
        float y = fmaf(e.y * alpha, w4.y, fmaf(nmr, w4.y, b4.y)) * SC;
        _Float16 h = (_Float16)y; hi4[1] = h; lo4[1] = (_Float16)(y - (float)h);
      }
      {
        float y = fmaf(e.z * alpha, w4.z, fmaf(nmr, w4.z, b4.z)) * SC;
        _Float16 h = (_Float16)y; hi4[2] = h; lo4[2] = (_Float16)(y - (float)h);
      }
      {
        float y = fmaf(e.w * alpha, w4.w, fmaf(nmr, w4.w, b4.w)) * SC;
        _Float16 h = (_Float16)y; hi4[3] = h; lo4[3] = (_Float16)(y - (float)h);
      }
      *reinterpret_cast<f16x4*>(&As_hi[row * LDA + c4 * 4]) = hi4;
      *reinterpret_cast<f16x4*>(&As_lo[row * LDA + c4 * 4]) = lo4;
    }
    __syncthreads();

    // ---- A fragments from LDS (A[m=lane&15][k=quad*8+j]) ----
    f16x8 ah[4], al[4];
#pragma unroll
    for (int mi = 0; mi < 4; ++mi) {
      int r = rowhalf * 64 + mi * 16 + ln16;
      ah[mi] = *reinterpret_cast<const f16x8*>(&As_hi[r * LDA + quad * 8]);
      al[mi] = *reinterpret_cast<const f16x8*>(&As_lo[r * LDA + quad * 8]);
    }
    // ---- B fragments straight from global (frag-order, coalesced 1KB/wave) ----
    f16x8 bh[4], bl[4];
#pragma unroll
    for (int nj = 0; nj < 4; ++nj) {
      int g = ht * 8 + colhalf * 4 + nj;
      int c = ((g * 32 + ks) * 4 + quad) * 16 + ln16;
      bh[nj] = whi[c];
      bl[nj] = wlo[c];
    }
    // ---- 3-product split-f16 MFMA ----
#pragma unroll
    for (int mi = 0; mi < 4; ++mi)
#pragma unroll
      for (int nj = 0; nj < 4; ++nj) {
        acc[mi][nj] = __builtin_amdgcn_mfma_f32_16x16x32_f16(ah[mi], bh[nj], acc[mi][nj], 0, 0, 0);
        acc[mi][nj] = __builtin_amdgcn_mfma_f32_16x16x32_f16(al[mi], bh[nj], acc[mi][nj], 0, 0, 0);
        acc[mi][nj] = __builtin_amdgcn_mfma_f32_16x16x32_f16(ah[mi], bl[nj], acc[mi][nj], 0, 0, 0);
      }
  }

  // ---- epilogue: bias + exact GELU + fc2 weight, reduce over hidden ----
  float s[4][4];
#pragma unroll
  for (int mi = 0; mi < 4; ++mi)
#pragma unroll
    for (int r = 0; r < 4; ++r) s[mi][r] = 0.f;

#pragma unroll
  for (int nj = 0; nj < 4; ++nj) {
    int h = ht * HT + colhalf * 64 + nj * 16 + ln16;
    float b1 = 0.f, w2 = 0.f;
    if (h < HID_) { b1 = fc1b[h]; w2 = fc2w[h]; }
#pragma unroll
    for (int mi = 0; mi < 4; ++mi)
#pragma unroll
      for (int r = 0; r < 4; ++r) {
        float v = acc[mi][nj][r] * INV_SC2 + b1;
        float gel = 0.5f * v * (1.f + erff(v * 0.70710678118654752440f));
        s[mi][r] = fmaf(gel, w2, s[mi][r]);
      }
  }
  // reduce across the 16 lanes of each quad-row group (n dimension)
#pragma unroll
  for (int mi = 0; mi < 4; ++mi)
#pragma unroll
    for (int r = 0; r < 4; ++r) {
      float v = s[mi][r];
      v += __shfl_xor(v, 1, 64);
      v += __shfl_xor(v, 2, 64);
      v += __shfl_xor(v, 4, 64);
      v += __shfl_xor(v, 8, 64);
      s[mi][r] = v;
    }
  __syncthreads();
  if (ln16 == 0) {
#pragma unroll
    for (int mi = 0; mi < 4; ++mi)
#pragma unroll
      for (int r = 0; r < 4; ++r)
        red[colhalf][rowhalf * 64 + mi * 16 + quad * 4 + r] = s[mi][r];
  }
  __syncthreads();
  if (tid < MT)
    partial[(size_t)ht * N_TOK + m0 + tid] = red[0][tid] + red[1][tid];
}

// ---------------- Kernel 3: slab-reduce + masked softmax + entropy + K + z ----------
__global__ __launch_bounds__(1024) void softmax_kernel(
    const float* __restrict__ partial, const float* __restrict__ fc2b,
    const float* __restrict__ attn,
    float* __restrict__ out_z, float* __restrict__ rowent, float* __restrict__ rowK)
{
  __shared__ float buf[1024];
  int b = blockIdx.x, tid = threadIdx.x;
  const float* arow = attn + b * T_;
  float sv[4], av[4];
  float f2b = fc2b[0];
#pragma unroll
  for (int q = 0; q < 4; ++q) {
    int t = tid + q * 1024;
    av[q] = arow[t];
    float sc = f2b;
#pragma unroll
    for (int p = 0; p < NHT; ++p) sc += partial[(size_t)p * N_TOK + b * T_ + t];
    sv[q] = (av[q] == 0.f) ? -1e9f : sc;
  }
  float m = fmaxf(fmaxf(sv[0], sv[1]), fmaxf(sv[2], sv[3]));
  buf[tid] = m; __syncthreads();
  for (int s = 512; s > 0; s >>= 1) { if (tid < s) buf[tid] = fmaxf(buf[tid], buf[tid + s]); __syncthreads(); }
  m = buf[0]; __syncthreads();
  float e[4]; float es = 0.f, as = 0.f;
#pragma unroll
  for (int q = 0; q < 4; ++q) { e[q] = expf(sv[q] - m); es += e[q]; as += av[q]; }
  buf[tid] = es; __syncthreads();
  for (int s = 512; s > 0; s >>= 1) { if (tid < s) buf[tid] += buf[tid + s]; __syncthreads(); }
  es = buf[0]; __syncthreads();
  buf[tid] = as; __syncthreads();
  for (int s = 512; s > 0; s >>= 1) { if (tid < s) buf[tid] += buf[tid + s]; __syncthreads(); }
  as = buf[0]; __syncthreads();

  float K = fmaxf(1.f, rintf(RHO_ * as));
  float inv = 1.f / es;
  float ent = 0.f;
#pragma unroll
  for (int q = 0; q < 4; ++q) {
    float p = e[q] * inv;
    out_z[b * T_ + tid + q * 1024] = K * p;
    ent -= p * logf(p + 1e-12f);
  }
  buf[tid] = ent; __syncthreads();
  for (int s = 512; s > 0; s >>= 1) { if (tid < s) buf[tid] += buf[tid + s]; __syncthreads(); }
  if (tid == 0) {
    rowent[b] = buf[0] / logf(fmaxf(as, 1.f));
    rowK[b] = K;
  }
}

// ---------------- Kernel 4: per-row exact top-K mask (stable ties) + scalar out ----
__global__ __launch_bounds__(1024) void topk_kernel(
    const float* __restrict__ zall, float* __restrict__ g,
    const float* __restrict__ rowent, const float* __restrict__ rowK,
    float* __restrict__ out_scalar)
{
  __shared__ float sm[T_];
  __shared__ int s_first, s_last;
  int b = blockIdx.x, tid = threadIdx.x;
  const float* zrow = zall + b * T_;
  for (int t = tid; t < T_; t += 1024) sm[t] = zrow[t];
  __syncthreads();
  for (int k = 2; k <= T_; k <<= 1) {
    for (int j = k >> 1; j > 0; j >>= 1) {
      for (int t = tid; t < T_; t += 1024) {
        int ixj = t ^ j;
        if (ixj > t) {
          float a = sm[t], c = sm[ixj];
          bool desc = ((t & k) == 0);
          if (desc ? (a < c) : (a > c)) { sm[t] = c; sm[ixj] = a; }
        }
      }
      __syncthreads();
    }
  }
  int K = (int)rowK[b];
  float thr = sm[K - 1];
  if (tid == 0) { s_first = T_; s_last = -1; }
  __syncthreads();
  for (int t = tid; t < T_; t += 1024) {
    if (sm[t] == thr) { atomicMin(&s_first, t); atomicMax(&s_last, t); }
  }
  __syncthreads();
  int cgt = s_first;
  int eqTotal = s_last - s_first + 1;
  int need = K - cgt;
  float* grow = g + b * T_;
  bool allEq = (eqTotal == need);
  for (int t = tid; t < T_; t += 1024) {
    float zv = zrow[t];
    if (zv > thr) grow[t] = 1.f;
    else if (zv < thr) grow[t] = 0.f;
    else if (allEq) grow[t] = 1.f;
  }
  __syncthreads();
  if (!allEq && tid == 0) {
    int cnt = 0;
    for (int t = 0; t < T_; ++t) {
      float zv = zrow[t];
      if (zv == thr) { grow[t] = (cnt < need) ? 1.f : 0.f; ++cnt; }
    }
  }
  if (b == 0 && tid == 0) {
    float s = 0.f;
    for (int i = 0; i < B_; ++i) s += rowent[i];
    out_scalar[0] = s * (1.f / B_);
  }
}

extern "C" void kernel_launch(void* const* d_in, const int* in_sizes, int n_in,
                              void* d_out, int out_size, void* d_ws, size_t ws_size,
                              hipStream_t stream)
{
  const float* emb  = (const float*)d_in[0];
  const float* attn = (const float*)d_in[1];
  const float* lnw  = (const float*)d_in[2];
  const float* lnb  = (const float*)d_in[3];
  const float* fc1w = (const float*)d_in[4];
  const float* fc1b = (const float*)d_in[5];
  const float* fc2w = (const float*)d_in[6];
  const float* fc2b = (const float*)d_in[7];

  float* out = (float*)d_out;
  float* g  = out;                 // [B,T]
  float* z  = out + N_TOK;         // [B,T]
  float* ns = out + 2 * N_TOK;     // [1]

  float* mu      = (float*)d_ws;           // N_TOK
  float* rstd    = mu + N_TOK;             // N_TOK
  float* partial = rstd + N_TOK;           // NHT * N_TOK
  float* rowent  = partial + NHT * N_TOK;  // 16
  float* rowK    = rowent + 16;            // 16
  f16x8* whi     = (f16x8*)(rowK + 16);    // WCHUNKS chunks (16B each)
  f16x8* wlo     = whi + WCHUNKS;
  // total ws use: ~9.2 MB

  ln_stats_kernel<<<N_TOK / 4, 256, 0, stream>>>(emb, attn, mu, rstd);
  wsplit_kernel<<<(WCHUNKS + 255) / 256, 256, 0, stream>>>(fc1w, whi, wlo);
  dim3 grid(N_TOK / MT, NHT);
  mfma_score_kernel<<<grid, 256, 0, stream>>>(emb, attn, lnw, lnb, mu, rstd,
                                              whi, wlo, fc1b, fc2w, partial);
  softmax_kernel<<<B_, 1024, 0, stream>>>(partial, fc2b, attn, z, rowent, rowK);
  topk_kernel<<<B_, 1024, 0, stream>>>(z, g, rowent, rowK, ns);
}